// Round 10
// baseline (54.173 us; speedup 1.0000x reference)
//
#include <hip/hip_runtime.h>

// CTC batch cost (Keras ctc_batch_cost), B=256, T=512, C=128, L=64.
// TWO batch elements per 64-lane wave (128 blocks): the two independent
// recurrence chains interleave so in-order issue fills each chain's
// dependency stalls with the other batch's instructions.
// Linear-domain recurrence, per-lane pow2 exponent (no trans on chain):
//   A0' = (A0 + P1)*pb ; A1' = (A1 + A0 + skipf*P1)*pl ; A2' = (A2+A1)*pb
// P1 = DPP wave_shr:1 of A1, aligned by exact 2^(e_prev-e). Renorm every
// 4 steps (value-preserving: A*2^-ex, e+=ex -> always safe to apply).
// Fat variant (t<128): per-step dead-lane exponent adoption.
// Staging: 32-row chunks/batch via global_load_lds, dbuf, counted vmcnt(32).

#define B_ 256
#define NB 128          // blocks; block b handles batches b and b+NB
#define T_ 512
#define C_ 128
#define L_ 64
#define BLANK_ 127
#define EPSF (1e-7f)
#define CHUNK 32
#define LN2F 0.6931471805599453f

#define EXP2(x) __builtin_amdgcn_exp2f(x)   // v_exp_f32 (base-2)
#define LOG2(x) __builtin_amdgcn_logf(x)    // v_log_f32 (base-2)

__device__ __forceinline__ float lse2_2(float a, float b) {
    float m = fmaxf(a, b);
    float d = fminf(a, b) - m;
    return m + LOG2(1.0f + EXP2(d));
}

__device__ __forceinline__ float dppf(float x) {  // lane i <- i-1; lane0 <- 0
    return __int_as_float(__builtin_amdgcn_update_dpp(
        0, __float_as_int(x), 0x138, 0xf, 0xf, false));
}
__device__ __forceinline__ int dppi(int x) {
    return __builtin_amdgcn_update_dpp(0, x, 0x138, 0xf, 0xf, false);
}

__device__ __forceinline__ float delta_scale(int ep, int e) {
    int d = ep - e;                       // 2^clamp(d,±126), exact
    d = d < -126 ? -126 : d;
    d = d > 126 ? 126 : d;
    return __int_as_float((d + 127) << 23);
}

__device__ __forceinline__ void renorm3(float& A0, float& A1, float& A2, int& e) {
    float m = fmaxf(fmaxf(A0, A1), A2);
    const int mb = __float_as_int(m);
    const bool valid = (unsigned)(mb - 0x00800000) < 0x7f000000u;  // normal finite
    int ex = (mb >> 23) - 127;
    ex = valid ? ex : 0;
    const float s = __int_as_float((127 - ex) << 23);  // exact 2^-ex
    A0 *= s; A1 *= s; A2 *= s;
    e += ex;
}

__device__ __forceinline__ void stage_chunk(const float* gsrc, float* ldst, int lane) {
#pragma unroll
    for (int i = 0; i < CHUNK / 2; ++i) {
        __builtin_amdgcn_global_load_lds(
            (const __attribute__((address_space(1))) void*)(gsrc + i * 256 + lane * 4),
            (__attribute__((address_space(3))) void*)(ldst + i * 256),
            16, 0, 0);
    }
}

__device__ __forceinline__ void lean_step(float& A0, float& A1, float& A2,
                                          float sc, float skipf,
                                          float pb, float pl, bool v) {
    const float P1 = dppf(A1) * sc;
    const float A0o = A0, A1o = A1;
    const float nA0 = (A0o + P1) * pb;
    const float t   = fmaf(skipf, P1, A0o);
    const float nA1 = (A1o + t) * pl;
    const float nA2 = (A2 + A1o) * pb;
    A0 = v ? nA0 : A0o;
    A1 = v ? nA1 : A1o;
    A2 = v ? nA2 : A2;
}

__device__ __forceinline__ void fat_step(float& A0, float& A1, float& A2, int& e,
                                         float skipf, float pb, float pl, bool v) {
    const float p1 = dppf(A1);
    const int   ep = dppi(e);
    const bool dead = (fmaxf(A0, A1) == 0.0f);
    const int   e1 = dead ? ep : e;       // adopt neighbor exponent if dead
    const float sc = delta_scale(ep, e1);
    const float P1 = p1 * sc;
    const float A0o = A0, A1o = A1;
    const float nA0 = (A0o + P1) * pb;
    const float t   = fmaf(skipf, P1, A0o);
    const float nA1 = (A1o + t) * pl;
    const float nA2 = (A2 + A1o) * pb;
    A0 = v ? nA0 : A0o;
    A1 = v ? nA1 : A1o;
    A2 = v ? nA2 : A2;
    e  = v ? e1 : e;
}

template<bool FULL0>   // FULL0=false: skip u==0 (chunk 0 base 0; t=0 via init)
__device__ __forceinline__ void fat_pair(
    const float* __restrict__ LA, const float* __restrict__ LB, int base,
    int labelA, int labelB, float skipfA, float skipfB,
    float pbvA, float pbvB,
    float& A0a, float& A1a, float& A2a, int& ea,
    float& A0b, float& A1b, float& A2b, int& eb)
{
    float plA[16], plB[16];
#pragma unroll
    for (int u = 0; u < 16; ++u) {
        plA[u] = LA[(base + u) * C_ + labelA];
        plB[u] = LB[(base + u) * C_ + labelB];
    }
#pragma unroll
    for (int u = 0; u < 16; ++u) { plA[u] += EPSF; plB[u] += EPSF; }
#pragma unroll
    for (int u = 0; u < 16; ++u) {
        const float pbA = __int_as_float(
            __builtin_amdgcn_readlane(__float_as_int(pbvA), base + u));
        const float pbB = __int_as_float(
            __builtin_amdgcn_readlane(__float_as_int(pbvB), base + u));
        const bool v = FULL0 || (u >= 1);
        fat_step(A0a, A1a, A2a, ea, skipfA, pbA, plA[u], v);
        fat_step(A0b, A1b, A2b, eb, skipfB, pbB, plB[u], v);
        if ((u & 3) == 3) { renorm3(A0a, A1a, A2a, ea); renorm3(A0b, A1b, A2b, eb); }
    }
}

template<bool GUARD>
__device__ __forceinline__ void lean_pair(
    const float* __restrict__ LA, const float* __restrict__ LB, int base,
    int labelA, int labelB, float skipfA, float skipfB,
    float pbvA, float pbvB, int hiA, int hiB,
    float& A0a, float& A1a, float& A2a, int& ea, float& sca,
    float& A0b, float& A1b, float& A2b, int& eb, float& scb)
{
    float plA[16], plB[16];
#pragma unroll
    for (int u = 0; u < 16; ++u) {
        plA[u] = LA[(base + u) * C_ + labelA];
        plB[u] = LB[(base + u) * C_ + labelB];
    }
#pragma unroll
    for (int u = 0; u < 16; ++u) { plA[u] += EPSF; plB[u] += EPSF; }
#pragma unroll
    for (int u = 0; u < 16; ++u) {
        const float pbA = __int_as_float(
            __builtin_amdgcn_readlane(__float_as_int(pbvA), base + u));
        const float pbB = __int_as_float(
            __builtin_amdgcn_readlane(__float_as_int(pbvB), base + u));
        const bool vA = GUARD ? (u < hiA) : true;   // wave-uniform
        const bool vB = GUARD ? (u < hiB) : true;
        lean_step(A0a, A1a, A2a, sca, skipfA, pbA, plA[u], vA);
        lean_step(A0b, A1b, A2b, scb, skipfB, pbB, plB[u], vB);
        if ((u & 3) == 3) {
            renorm3(A0a, A1a, A2a, ea);             // value-preserving: no guard
            renorm3(A0b, A1b, A2b, eb);
            sca = delta_scale(dppi(ea), ea);
            scb = delta_scale(dppi(eb), eb);
        }
    }
}

__global__ __launch_bounds__(64) void ctc_fwd_kernel(
    const int* __restrict__ y_true, const float* __restrict__ y_pred,
    const int* __restrict__ input_len, const int* __restrict__ label_len,
    float* __restrict__ out)
{
    __shared__ float lds[2][2][CHUNK * C_];   // [batch][dbuf], 64 KB
    const int b0 = blockIdx.x, b1 = b0 + NB;
    const int lane = threadIdx.x;
    const float* __restrict__ PA = y_pred + (size_t)b0 * T_ * C_;
    const float* __restrict__ PB = y_pred + (size_t)b1 * T_ * C_;

    const int labelA = y_true[b0 * L_ + lane];
    const int labelB = y_true[b1 * L_ + lane];
    const int lpA = __shfl_up(labelA, 1);
    const int lpB = __shfl_up(labelB, 1);
    const float skipfA = (lane > 0 && labelA != lpA) ? 1.0f : 0.0f;
    const float skipfB = (lane > 0 && labelB != lpB) ? 1.0f : 0.0f;

    const int ilA = input_len[b0], ilB = input_len[b1];
    const int tendA = ilA < T_ ? ilA : T_;
    const int tendB = ilB < T_ ? ilB : T_;
    const int labA = label_len[b0];
    const int labB = label_len[b1];
    const int nA = (tendA + CHUNK - 1) / CHUNK;   // >= 8
    const int nB = (tendB + CHUNK - 1) / CHUNK;
    const int nmax = nA > nB ? nA : nB;

    stage_chunk(PA, &lds[0][0][0], lane);
    stage_chunk(PB, &lds[1][0][0], lane);
    stage_chunk(PA + CHUNK * C_, &lds[0][1][0], lane);
    stage_chunk(PB + CHUNK * C_, &lds[1][1][0], lane);

    float A0a = 0.0f, A1a = 0.0f, A2a = 0.0f, sca = 1.0f; int ea = 0;
    float A0b = 0.0f, A1b = 0.0f, A2b = 0.0f, scb = 1.0f; int eb = 0;

    for (int c = 0; c < nmax; ++c) {
        if (c + 1 < nmax) asm volatile("s_waitcnt vmcnt(32)" ::: "memory");
        else              asm volatile("s_waitcnt vmcnt(0)" ::: "memory");
        const float* __restrict__ LA = &lds[0][c & 1][0];
        const float* __restrict__ LB = &lds[1][c & 1][0];
        const float pbvA = LA[(lane & 31) * C_ + BLANK_] + EPSF;
        const float pbvB = LB[(lane & 31) * C_ + BLANK_] + EPSF;

        if (c == 0) {
            A0a = (lane == 0) ? LA[BLANK_] + EPSF : 0.0f;
            A1a = (lane == 0) ? LA[labelA] + EPSF : 0.0f;
            A0b = (lane == 0) ? LB[BLANK_] + EPSF : 0.0f;
            A1b = (lane == 0) ? LB[labelB] + EPSF : 0.0f;
            fat_pair<false>(LA, LB, 0, labelA, labelB, skipfA, skipfB, pbvA, pbvB,
                            A0a, A1a, A2a, ea, A0b, A1b, A2b, eb);
            fat_pair<true >(LA, LB, 16, labelA, labelB, skipfA, skipfB, pbvA, pbvB,
                            A0a, A1a, A2a, ea, A0b, A1b, A2b, eb);
        } else if (c < 4) {                 // t < 128: dead lanes possible
            fat_pair<true>(LA, LB, 0, labelA, labelB, skipfA, skipfB, pbvA, pbvB,
                           A0a, A1a, A2a, ea, A0b, A1b, A2b, eb);
            fat_pair<true>(LA, LB, 16, labelA, labelB, skipfA, skipfB, pbvA, pbvB,
                           A0a, A1a, A2a, ea, A0b, A1b, A2b, eb);
        } else {
            const int remA = tendA - c * CHUNK;
            const int remB = tendB - c * CHUNK;
            if (remA >= CHUNK && remB >= CHUNK) {   // common fast path
                lean_pair<false>(LA, LB, 0, labelA, labelB, skipfA, skipfB,
                                 pbvA, pbvB, 16, 16,
                                 A0a, A1a, A2a, ea, sca, A0b, A1b, A2b, eb, scb);
                lean_pair<false>(LA, LB, 16, labelA, labelB, skipfA, skipfB,
                                 pbvA, pbvB, 16, 16,
                                 A0a, A1a, A2a, ea, sca, A0b, A1b, A2b, eb, scb);
            } else {                                // tail: per-batch bounds
                lean_pair<true>(LA, LB, 0, labelA, labelB, skipfA, skipfB,
                                pbvA, pbvB, remA, remB,
                                A0a, A1a, A2a, ea, sca, A0b, A1b, A2b, eb, scb);
                lean_pair<true>(LA, LB, 16, labelA, labelB, skipfA, skipfB,
                                pbvA, pbvB, remA - 16, remB - 16,
                                A0a, A1a, A2a, ea, sca, A0b, A1b, A2b, eb, scb);
            }
        }
        if (c == 3) {                        // fat -> lean handoff
            sca = delta_scale(dppi(ea), ea);
            scb = delta_scale(dppi(eb), eb);
        }
        if (c + 2 < nmax) {
            stage_chunk(PA + (size_t)(c + 2) * CHUNK * C_, &lds[0][c & 1][0], lane);
            stage_chunk(PB + (size_t)(c + 2) * CHUNK * C_, &lds[1][c & 1][0], lane);
        }
    }

    {   // epilogue batch A
        const float ef = (float)ea;
        const float l0 = LOG2(A0a) + ef;
        const float l1 = LOG2(A1a) + ef;
        const float l2 = LOG2(A2a) + ef;
        const float a_prev = __shfl(l1, labA - 1);
        const float a_last = (labA >= L_) ? __shfl(l2, 63) : __shfl(l0, labA);
        if (lane == 0) out[b0] = -LN2F * lse2_2(a_last, a_prev);
    }
    {   // epilogue batch B
        const float ef = (float)eb;
        const float l0 = LOG2(A0b) + ef;
        const float l1 = LOG2(A1b) + ef;
        const float l2 = LOG2(A2b) + ef;
        const float a_prev = __shfl(l1, labB - 1);
        const float a_last = (labB >= L_) ? __shfl(l2, 63) : __shfl(l0, labB);
        if (lane == 0) out[b1] = -LN2F * lse2_2(a_last, a_prev);
    }
}

extern "C" void kernel_launch(void* const* d_in, const int* in_sizes, int n_in,
                              void* d_out, int out_size, void* d_ws, size_t ws_size,
                              hipStream_t stream) {
    const int*   y_true    = (const int*)d_in[0];
    const float* y_pred    = (const float*)d_in[1];
    const int*   input_len = (const int*)d_in[2];
    const int*   label_len = (const int*)d_in[3];
    float* out = (float*)d_out;

    ctc_fwd_kernel<<<NB, 64, 0, stream>>>(y_true, y_pred, input_len, label_len, out);
}

// Round 11
// 28.954 us; speedup vs baseline: 1.8710x; 1.8710x over previous
//
#include <hip/hip_runtime.h>

// CTC batch cost (Keras ctc_batch_cost), B=256, T=512, C=128, L=64.
// One 64-lane wave per batch element (256 blocks). Linear-domain recurrence
// with per-lane pow2 exponent tracking (no transcendentals on the chain):
//   A0' = (A0 + P1)*pb ; A1' = (A1 + A0 + skipf*P1)*pl ; A2' = (A2+A1)*pb
// P1 = DPP wave_shr:1 of A1, aligned by exact 2^(e_prev-e). Renorm every 4
// steps (value-preserving). Fat variant (t<128): dead-lane exponent adoption.
// KEY CHANGE vs r9: Phase A (16 LDS gathers + 16 readlane blank probs) is
// fenced with sched_barrier(0) and register-pinned so the compiler cannot
// sink the ds_reads into the step loop -> one lgkmcnt drain per 16 steps,
// step loop is pure-register VALU.
// Staging: 32-row chunks via global_load_lds, double-buffered, counted vmcnt.

#define B_ 256
#define T_ 512
#define C_ 128
#define L_ 64
#define BLANK_ 127
#define EPSF (1e-7f)
#define CHUNK 32
#define LN2F 0.6931471805599453f

#define EXP2(x) __builtin_amdgcn_exp2f(x)   // v_exp_f32 (base-2)
#define LOG2(x) __builtin_amdgcn_logf(x)    // v_log_f32 (base-2)

__device__ __forceinline__ float lse2_2(float a, float b) {
    float m = fmaxf(a, b);
    float d = fminf(a, b) - m;
    return m + LOG2(1.0f + EXP2(d));
}

__device__ __forceinline__ float dppf(float x) {  // lane i <- i-1; lane0 <- 0
    return __int_as_float(__builtin_amdgcn_update_dpp(
        0, __float_as_int(x), 0x138, 0xf, 0xf, false));
}
__device__ __forceinline__ int dppi(int x) {
    return __builtin_amdgcn_update_dpp(0, x, 0x138, 0xf, 0xf, false);
}

__device__ __forceinline__ float delta_scale(int ep, int e) {
    int d = ep - e;                       // 2^clamp(d,±126), exact bits
    d = d < -126 ? -126 : d;
    d = d > 126 ? 126 : d;
    return __int_as_float((d + 127) << 23);
}

__device__ __forceinline__ void renorm3(float& A0, float& A1, float& A2, int& e) {
    float m = fmaxf(fmaxf(A0, A1), A2);
    const int mb = __float_as_int(m);
    const bool valid = (unsigned)(mb - 0x00800000) < 0x7f000000u;  // normal finite
    int ex = (mb >> 23) - 127;
    ex = valid ? ex : 0;
    const float s = __int_as_float((127 - ex) << 23);  // exact 2^-ex
    A0 *= s; A1 *= s; A2 *= s;
    e += ex;
}

__device__ __forceinline__ void stage_chunk(const float* gsrc, float* ldst, int lane) {
#pragma unroll
    for (int i = 0; i < CHUNK / 2; ++i) {
        __builtin_amdgcn_global_load_lds(
            (const __attribute__((address_space(1))) void*)(gsrc + i * 256 + lane * 4),
            (__attribute__((address_space(3))) void*)(ldst + i * 256),
            16, 0, 0);
    }
}

struct Probs { float pl[16]; float pb[16]; };

__device__ __forceinline__ void loadA(const float* __restrict__ Lb, int base,
                                      int label, float pbv, Probs& P) {
#pragma unroll
    for (int u = 0; u < 16; ++u)
        P.pl[u] = Lb[(base + u) * C_ + label];        // per-lane gather
#pragma unroll
    for (int u = 0; u < 16; ++u)
        P.pb[u] = __int_as_float(
            __builtin_amdgcn_readlane(__float_as_int(pbv), base + u));  // uniform
}

__device__ __forceinline__ void finishA(Probs& P) {
#pragma unroll
    for (int u = 0; u < 16; ++u) {
        P.pl[u] += EPSF;
        asm volatile("" : "+v"(P.pl[u]));             // pin in VGPR; no sinking
    }
}

template<bool FULL>   // !FULL: only steps u in [lo,hi) update (wave-uniform)
__device__ __forceinline__ void fat_group(const Probs& P, int lo, int hi,
    float skipf, float& A0, float& A1, float& A2, int& e)
{
#pragma unroll
    for (int u = 0; u < 16; ++u) {
        const float p1 = dppf(A1);
        const int   ep = dppi(e);
        const bool dead = (fmaxf(A0, A1) == 0.0f);
        const int   e1 = dead ? ep : e;               // adopt neighbor exp if dead
        const float sc = delta_scale(ep, e1);
        const float P1 = p1 * sc;
        const float A0o = A0, A1o = A1;
        const float nA0 = (A0o + P1) * P.pb[u];
        const float t   = fmaf(skipf, P1, A0o);
        const float nA1 = (A1o + t) * P.pl[u];
        const float nA2 = (A2 + A1o) * P.pb[u];
        if (FULL) { A0 = nA0; A1 = nA1; A2 = nA2; e = e1; }
        else {
            const bool v = (u >= lo) & (u < hi);
            A0 = v ? nA0 : A0o; A1 = v ? nA1 : A1o;
            A2 = v ? nA2 : A2;  e  = v ? e1 : e;
        }
        if ((u & 3) == 3) renorm3(A0, A1, A2, e);
    }
}

template<bool GUARD>
__device__ __forceinline__ void lean_group(const Probs& P, int hi, float skipf,
    float& A0, float& A1, float& A2, int& e, float& sc)
{
#pragma unroll
    for (int u = 0; u < 16; ++u) {
        const float P1 = dppf(A1) * sc;
        const float A0o = A0, A1o = A1;
        const float nA0 = (A0o + P1) * P.pb[u];
        const float t   = fmaf(skipf, P1, A0o);
        const float nA1 = (A1o + t) * P.pl[u];
        const float nA2 = (A2 + A1o) * P.pb[u];
        if (GUARD) {
            const bool v = u < hi;                    // wave-uniform
            A0 = v ? nA0 : A0o; A1 = v ? nA1 : A1o; A2 = v ? nA2 : A2;
        } else { A0 = nA0; A1 = nA1; A2 = nA2; }
        if ((u & 3) == 3) {                           // value-preserving: no guard
            renorm3(A0, A1, A2, e);
            sc = delta_scale(dppi(e), e);
        }
    }
}

__global__ __launch_bounds__(64) void ctc_fwd_kernel(
    const int* __restrict__ y_true, const float* __restrict__ y_pred,
    const int* __restrict__ input_len, const int* __restrict__ label_len,
    float* __restrict__ out)
{
    __shared__ float lds[2][CHUNK * C_];
    const int b = blockIdx.x;
    const int lane = threadIdx.x;
    const float* __restrict__ P = y_pred + (size_t)b * T_ * C_;

    const int label = y_true[b * L_ + lane];
    const int lprev = __shfl_up(label, 1);
    const float skipf = (lane > 0 && label != lprev) ? 1.0f : 0.0f;

    const int in_len = input_len[b];
    const int lab    = label_len[b];
    const int tend = in_len < T_ ? in_len : T_;
    const int nchunks = (tend + CHUNK - 1) / CHUNK;   // >= 8 (tend >= 256)

    stage_chunk(P, &lds[0][0], lane);
    stage_chunk(P + CHUNK * C_, &lds[1][0], lane);

    float A0 = 0.0f, A1 = 0.0f, A2 = 0.0f, sc = 1.0f;
    int e = 0;

    for (int c = 0; c < nchunks; ++c) {
        if (c + 1 < nchunks) asm volatile("s_waitcnt vmcnt(16)" ::: "memory");
        else                 asm volatile("s_waitcnt vmcnt(0)" ::: "memory");
        const float* __restrict__ Lb = lds[c & 1];
        const float pbv = Lb[(lane & 31) * C_ + BLANK_] + EPSF;  // rows 0..31

        Probs Pg0, Pg1;
        loadA(Lb, 0, label, pbv, Pg0);
        __builtin_amdgcn_sched_barrier(0);            // loads stay issued here
        finishA(Pg0);
        loadA(Lb, 16, label, pbv, Pg1);               // g1 loads cover g0 compute
        __builtin_amdgcn_sched_barrier(0);

        if (c == 0) {
            A0 = (lane == 0) ? Lb[BLANK_] + EPSF : 0.0f;   // t=0 init
            A1 = (lane == 0) ? Lb[label]  + EPSF : 0.0f;
            fat_group<false>(Pg0, 1, 16, skipf, A0, A1, A2, e);
            finishA(Pg1);
            fat_group<true >(Pg1, 0, 0, skipf, A0, A1, A2, e);
        } else if (c < 4) {                           // t < 128: dead lanes possible
            fat_group<true>(Pg0, 0, 0, skipf, A0, A1, A2, e);
            finishA(Pg1);
            fat_group<true>(Pg1, 0, 0, skipf, A0, A1, A2, e);
        } else {
            if (c == 4) sc = delta_scale(dppi(e), e); // fat -> lean handoff
            const int rem = tend - c * CHUNK;
            if (rem >= CHUNK) {                       // common fast path
                lean_group<false>(Pg0, 16, skipf, A0, A1, A2, e, sc);
                finishA(Pg1);
                lean_group<false>(Pg1, 16, skipf, A0, A1, A2, e, sc);
            } else if (rem > 16) {
                lean_group<false>(Pg0, 16, skipf, A0, A1, A2, e, sc);
                finishA(Pg1);
                lean_group<true >(Pg1, rem - 16, skipf, A0, A1, A2, e, sc);
            } else {
                lean_group<true>(Pg0, rem, skipf, A0, A1, A2, e, sc);
            }
        }
        if (c + 2 < nchunks)
            stage_chunk(P + (size_t)(c + 2) * CHUNK * C_, &lds[c & 1][0], lane);
    }

    // back to log2 once; loss = -ln2 * logaddexp2(alpha[2lab], alpha[2lab-1])
    const float ef = (float)e;
    const float l0 = LOG2(A0) + ef;
    const float l1 = LOG2(A1) + ef;
    const float l2 = LOG2(A2) + ef;
    const float a_prev = __shfl(l1, lab - 1);            // state 2*lab-1
    const float a_last = (lab >= L_) ? __shfl(l2, 63)    // state 128
                                     : __shfl(l0, lab);  // state 2*lab
    if (lane == 0) out[b] = -LN2F * lse2_2(a_last, a_prev);
}

extern "C" void kernel_launch(void* const* d_in, const int* in_sizes, int n_in,
                              void* d_out, int out_size, void* d_ws, size_t ws_size,
                              hipStream_t stream) {
    const int*   y_true    = (const int*)d_in[0];
    const float* y_pred    = (const float*)d_in[1];
    const int*   input_len = (const int*)d_in[2];
    const int*   label_len = (const int*)d_in[3];
    float* out = (float*)d_out;

    ctc_fwd_kernel<<<B_, 64, 0, stream>>>(y_true, y_pred, input_len, label_len, out);
}

// Round 12
// 26.068 us; speedup vs baseline: 2.0781x; 1.1107x over previous
//
#include <hip/hip_runtime.h>

// CTC batch cost (Keras ctc_batch_cost), B=256, T=512, C=128, L=64.
// 256 blocks x 128 threads: wave0 = recurrence (consumer), wave1 = producer.
// Blank-normalized linear domain: states divided by G(t) = prod(pb+eps):
//   A0' = A0 + P1 ; A1' = (A1 + A0 + sk*P1)*ql ; A2' = A2 + A1
// with ql = (pl+eps)/(pb+eps). G tracked as wave-uniform log2 sum (producer).
// Per-lane pow2 exponent e, renorm every 4 steps (window drift <= 2^+-95: safe).
// P1 = DPP wave_shr:1 of A1, aligned by exact 2^(e_prev-e).
// Fat phase (t<128): dead-lane exponent adoption (state liveness <= 2*lane).
// Producer: stages raw probs (global_load_lds, counted vmcnt), computes
// ql[lane][row] (stride 36 dwords -> consumer reads 8x ds_read_b128/chunk),
// accumulates lg = sum log2(pb+eps). One s_barrier per chunk.

#define B_ 256
#define T_ 512
#define C_ 128
#define L_ 64
#define BLANK_ 127
#define EPSF (1e-7f)
#define CHUNK 32
#define QSTR 36            // ql row stride per lane (dwords); 144B, 16B-aligned
#define LN2F 0.6931471805599453f

#define EXP2(x) __builtin_amdgcn_exp2f(x)   // v_exp_f32 (base-2)
#define LOG2(x) __builtin_amdgcn_logf(x)    // v_log_f32 (base-2)

__device__ __forceinline__ float lse2_2(float a, float b) {
    float m = fmaxf(a, b);
    float d = fminf(a, b) - m;
    return m + LOG2(1.0f + EXP2(d));
}

__device__ __forceinline__ float dppf(float x) {  // lane i <- i-1; lane0 <- 0
    return __int_as_float(__builtin_amdgcn_update_dpp(
        0, __float_as_int(x), 0x138, 0xf, 0xf, false));
}
__device__ __forceinline__ int dppi(int x) {
    return __builtin_amdgcn_update_dpp(0, x, 0x138, 0xf, 0xf, false);
}

__device__ __forceinline__ float delta_scale(int ep, int e) {
    int d = ep - e;                       // exact 2^clamp(d,+-126)
    d = d < -126 ? -126 : d;
    d = d > 126 ? 126 : d;
    return __int_as_float((d + 127) << 23);
}

__device__ __forceinline__ void renorm(float& A0, float& A1, float& A2, int& e) {
    const float m = fmaxf(fmaxf(A0, A1), A2);
    const int ex = (__float_as_int(m) >> 23) - 127;   // m==0 -> -127 (harmless)
    const float s = __int_as_float((127 - ex) << 23); // exact 2^-ex
    A0 *= s; A1 *= s; A2 *= s;
    e += ex;
}

__device__ __forceinline__ void stage_chunk(const float* gsrc, float* ldst, int lane) {
#pragma unroll
    for (int i = 0; i < CHUNK / 2; ++i) {
        __builtin_amdgcn_global_load_lds(
            (const __attribute__((address_space(1))) void*)(gsrc + i * 256 + lane * 4),
            (__attribute__((address_space(3))) void*)(ldst + i * 256),
            16, 0, 0);
    }
}

__device__ __forceinline__ void produce_chunk(const float* __restrict__ rk,
        float* __restrict__ qd, int lane, int label, int t0, int tend, float& llg)
{
    const float pbv  = rk[(lane & 31) * C_ + BLANK_] + EPSF;
    const float rpb  = 1.0f / pbv;
    const float erpb = EPSF * rpb;
    const int t = t0 + lane;
    const bool lgv = (lane < 32) && (t >= 1) && (t < tend);
    llg += lgv ? LOG2(pbv) : 0.0f;
#pragma unroll
    for (int r = 0; r < CHUNK; ++r) {
        const float pl = rk[r * C_ + label];
        const float rb = __int_as_float(
            __builtin_amdgcn_readlane(__float_as_int(rpb), r));
        const float eb = __int_as_float(
            __builtin_amdgcn_readlane(__float_as_int(erpb), r));
        qd[lane * QSTR + r] = fmaf(pl, rb, eb);   // (pl+eps)/(pb+eps)
    }
}

__device__ __forceinline__ void fat_step(float& A0, float& A1, float& A2, int& e,
                                         float skipf, float ql) {
    const float p1 = dppf(A1);
    const int   ep = dppi(e);
    const bool dead = (A0 + A1) == 0.0f;          // nonneg states
    const int   e1 = dead ? ep : e;               // adopt neighbor exp if dead
    const float P1 = p1 * delta_scale(ep, e1);
    const float A0o = A0, A1o = A1;
    A0 = A0o + P1;
    const float t = fmaf(skipf, P1, A0o);
    A1 = (A1o + t) * ql;
    A2 = A2 + A1o;
    e  = e1;
}

__device__ __forceinline__ void lean_step(float& A0, float& A1, float& A2,
                                          float sc, float skipf, float ql) {
    const float P1 = dppf(A1) * sc;
    const float A0o = A0, A1o = A1;
    A0 = A0o + P1;
    const float t = fmaf(skipf, P1, A0o);
    A1 = (A1o + t) * ql;
    A2 = A2 + A1o;
}

__global__ __launch_bounds__(128) void ctc_fwd_kernel(
    const int* __restrict__ y_true, const float* __restrict__ y_pred,
    const int* __restrict__ input_len, const int* __restrict__ label_len,
    float* __restrict__ out)
{
    __shared__ __align__(16) float raw[2][CHUNK * C_];     // 32 KB
    __shared__ __align__(16) float qlbuf[2][64 * QSTR];    // 18.4 KB
    __shared__ float extra[4];                             // initA1, initA0, lg

    const int b = blockIdx.x;
    const int tid = threadIdx.x;
    const int lane = tid & 63;
    const float* __restrict__ Pg = y_pred + (size_t)b * T_ * C_;
    const int label = y_true[b * L_ + lane];
    const int in_len = input_len[b];
    const int tend = in_len < T_ ? in_len : T_;            // >= 256
    const int nmax = (tend + CHUNK - 1) / CHUNK;           // 8..16

    if (tid >= 64) {
        // ------------------------- producer (wave 1) -------------------------
        float llg = 0.0f;
        stage_chunk(Pg, &raw[0][0], lane);
        stage_chunk(Pg + CHUNK * C_, &raw[1][0], lane);
        asm volatile("s_waitcnt vmcnt(16)" ::: "memory");  // chunk0 raw ready
        produce_chunk(&raw[0][0], &qlbuf[0][0], lane, label, 0, tend, llg);
        if (lane == 0) {
            extra[0] = raw[0][label] + EPSF;               // A1 init (s=1)
            extra[1] = raw[0][BLANK_] + EPSF;              // A0 init (s=0)
        }
        asm volatile("s_waitcnt lgkmcnt(0)" ::: "memory");
        __builtin_amdgcn_s_barrier();                      // B0
        for (int c = 0; c < nmax; ++c) {
            if (c + 2 < nmax)
                stage_chunk(Pg + (size_t)(c + 2) * CHUNK * C_, &raw[c & 1][0], lane);
            if (c + 1 < nmax) {
                if (c + 2 < nmax) asm volatile("s_waitcnt vmcnt(16)" ::: "memory");
                else              asm volatile("s_waitcnt vmcnt(0)" ::: "memory");
                produce_chunk(&raw[(c + 1) & 1][0], &qlbuf[(c + 1) & 1][0],
                              lane, label, (c + 1) * CHUNK, tend, llg);
            }
            asm volatile("s_waitcnt lgkmcnt(0)" ::: "memory");
            __builtin_amdgcn_s_barrier();                  // per-chunk
        }
#pragma unroll
        for (int off = 16; off >= 1; off >>= 1) llg += __shfl_xor(llg, off);
        if (lane == 0) extra[2] = llg;                     // lg = sum log2(pb+eps)
        asm volatile("s_waitcnt lgkmcnt(0)" ::: "memory");
        __builtin_amdgcn_s_barrier();                      // BF
    } else {
        // ------------------------- consumer (wave 0) -------------------------
        const int lprev = __shfl_up(label, 1);
        const float skipf = (lane > 0 && label != lprev) ? 1.0f : 0.0f;
        const int lab = label_len[b];
        __builtin_amdgcn_s_barrier();                      // B0

        float A0 = (lane == 0) ? extra[1] : 0.0f;
        float A1 = (lane == 0) ? extra[0] : 0.0f;
        float A2 = 0.0f, sc = 1.0f;
        int e = 0;

        // chunk 0 (fat, steps 1..31)
        {
            const float* qb = &qlbuf[0][lane * QSTR];
            float qlv[32];
#pragma unroll
            for (int k = 0; k < 8; ++k) {
                const float4 t4 = *reinterpret_cast<const float4*>(qb + 4 * k);
                qlv[4*k+0] = t4.x; qlv[4*k+1] = t4.y;
                qlv[4*k+2] = t4.z; qlv[4*k+3] = t4.w;
            }
            __builtin_amdgcn_sched_barrier(0);
#pragma unroll
            for (int u = 1; u < 32; ++u) {
                fat_step(A0, A1, A2, e, skipf, qlv[u]);
                if ((u & 3) == 3) renorm(A0, A1, A2, e);
            }
            __builtin_amdgcn_s_barrier();
        }
        // chunks 1..3 (fat)
        for (int c = 1; c < 4; ++c) {
            const float* qb = &qlbuf[c & 1][lane * QSTR];
            float qlv[32];
#pragma unroll
            for (int k = 0; k < 8; ++k) {
                const float4 t4 = *reinterpret_cast<const float4*>(qb + 4 * k);
                qlv[4*k+0] = t4.x; qlv[4*k+1] = t4.y;
                qlv[4*k+2] = t4.z; qlv[4*k+3] = t4.w;
            }
            __builtin_amdgcn_sched_barrier(0);
#pragma unroll
            for (int u = 0; u < 32; ++u) {
                fat_step(A0, A1, A2, e, skipf, qlv[u]);
                if ((u & 3) == 3) renorm(A0, A1, A2, e);
            }
            __builtin_amdgcn_s_barrier();
        }
        sc = delta_scale(dppi(e), e);
        // chunks 4.. (lean; guard only possible in last chunk)
        for (int c = 4; c < nmax; ++c) {
            const float* qb = &qlbuf[c & 1][lane * QSTR];
            float qlv[32];
#pragma unroll
            for (int k = 0; k < 8; ++k) {
                const float4 t4 = *reinterpret_cast<const float4*>(qb + 4 * k);
                qlv[4*k+0] = t4.x; qlv[4*k+1] = t4.y;
                qlv[4*k+2] = t4.z; qlv[4*k+3] = t4.w;
            }
            __builtin_amdgcn_sched_barrier(0);
            const int rem = tend - c * CHUNK;
            if (rem >= CHUNK) {
#pragma unroll
                for (int u = 0; u < 32; ++u) {
                    lean_step(A0, A1, A2, sc, skipf, qlv[u]);
                    if ((u & 3) == 3) {
                        renorm(A0, A1, A2, e);
                        sc = delta_scale(dppi(e), e);
                    }
                }
            } else {
#pragma unroll
                for (int u = 0; u < 32; ++u) {
                    const float A0o = A0, A1o = A1, A2o = A2;
                    lean_step(A0, A1, A2, sc, skipf, qlv[u]);
                    const bool v = u < rem;                // wave-uniform
                    A0 = v ? A0 : A0o; A1 = v ? A1 : A1o; A2 = v ? A2 : A2o;
                    if ((u & 3) == 3) {
                        renorm(A0, A1, A2, e);             // value-preserving
                        sc = delta_scale(dppi(e), e);
                    }
                }
            }
            __builtin_amdgcn_s_barrier();
        }
        __builtin_amdgcn_s_barrier();                      // BF
        const float lg = extra[2];
        const float ef = (float)e + lg;
        const float l0 = LOG2(A0) + ef;
        const float l1 = LOG2(A1) + ef;
        const float l2 = LOG2(A2) + ef;
        const float a_prev = __shfl(l1, lab - 1);          // state 2*lab-1
        const float a_last = (lab >= L_) ? __shfl(l2, 63)  // state 128
                                         : __shfl(l0, lab);
        if (lane == 0) out[b] = -LN2F * lse2_2(a_last, a_prev);
    }
}

extern "C" void kernel_launch(void* const* d_in, const int* in_sizes, int n_in,
                              void* d_out, int out_size, void* d_ws, size_t ws_size,
                              hipStream_t stream) {
    const int*   y_true    = (const int*)d_in[0];
    const float* y_pred    = (const float*)d_in[1];
    const int*   input_len = (const int*)d_in[2];
    const int*   label_len = (const int*)d_in[3];
    float* out = (float*)d_out;

    ctc_fwd_kernel<<<B_, 128, 0, stream>>>(y_true, y_pred, input_len, label_len, out);
}

// Round 13
// 24.329 us; speedup vs baseline: 2.2267x; 1.0715x over previous
//
#include <hip/hip_runtime.h>

// CTC batch cost (Keras ctc_batch_cost), B=256, T=512, C=128, L=64.
// 256 blocks x 128 threads: wave0 = recurrence (consumer), wave1 = producer.
// Blank-normalized linear domain with uniform 0.5/step decay folded into ql:
//   A0' = 0.5*(A0 + sc*A1prev) ; A1' = (A1 + A0 + sk*sc*A1prev)*ql'
//   ql' = 0.5*(pl+eps)/(pb+eps); G + decay accounted via lg + (tend-1).
// Per-lane pow2 exponent e, TRIGGER renorm: every 4 steps wave-votes
// max(A0,A1) outside [2^-24,2^24]; renorm block (exact 2^-k scales + sc
// update) runs only then. Dead lanes (m==0) never trigger; e stays 0 so
// first-contact scaling is exact -> no fat/lean split, single step kind.
// Producer: stages raw probs (global_load_lds, counted vmcnt), computes
// ql' with b128 writes, accumulates lg = sum log2(pb+eps). 1 barrier/chunk.

#define B_ 256
#define T_ 512
#define C_ 128
#define L_ 64
#define BLANK_ 127
#define EPSF (1e-7f)
#define CHUNK 32
#define QSTR 36            // ql row stride (dwords); 144B -> b128-aligned
#define LN2F 0.6931471805599453f

#define EXP2(x) __builtin_amdgcn_exp2f(x)   // v_exp_f32 (base-2)
#define LOG2(x) __builtin_amdgcn_logf(x)    // v_log_f32 (base-2)

__device__ __forceinline__ float lse2_2(float a, float b) {
    float m = fmaxf(a, b);
    float d = fminf(a, b) - m;
    return m + LOG2(1.0f + EXP2(d));
}

__device__ __forceinline__ float dppf(float x) {  // lane i <- i-1; lane0 <- 0
    return __int_as_float(__builtin_amdgcn_update_dpp(
        0, __float_as_int(x), 0x138, 0xf, 0xf, false));
}
__device__ __forceinline__ int dppi(int x) {
    return __builtin_amdgcn_update_dpp(0, x, 0x138, 0xf, 0xf, false);
}

__device__ __forceinline__ void stage_chunk(const float* gsrc, float* ldst, int lane) {
#pragma unroll
    for (int i = 0; i < CHUNK / 2; ++i) {
        __builtin_amdgcn_global_load_lds(
            (const __attribute__((address_space(1))) void*)(gsrc + i * 256 + lane * 4),
            (__attribute__((address_space(3))) void*)(ldst + i * 256),
            16, 0, 0);
    }
}

__device__ __forceinline__ void produce_chunk(const float* __restrict__ rk,
        float* __restrict__ qd, int lane, int label, int t0, int tend, float& llg)
{
    const float pbv  = rk[(lane & 31) * C_ + BLANK_] + EPSF;
    const float rpb  = 0.5f / pbv;            // 0.5 = uniform per-step decay
    const float erpb = EPSF * rpb;
    const int t = t0 + lane;
    const bool lgv = (lane < 32) && (t >= 1) && (t < tend);
    llg += lgv ? LOG2(pbv) : 0.0f;
#pragma unroll
    for (int k = 0; k < 8; ++k) {
        float q[4];
#pragma unroll
        for (int j = 0; j < 4; ++j) {
            const int r = 4 * k + j;
            const float pl = rk[r * C_ + label];
            const float rb = __int_as_float(
                __builtin_amdgcn_readlane(__float_as_int(rpb), r));
            const float eb = __int_as_float(
                __builtin_amdgcn_readlane(__float_as_int(erpb), r));
            q[j] = fmaf(pl, rb, eb);          // 0.5*(pl+eps)/(pb+eps)
        }
        *reinterpret_cast<float4*>(qd + lane * QSTR + 4 * k) =
            make_float4(q[0], q[1], q[2], q[3]);
    }
}

// trigger test + rare renorm block (wave-uniform branch)
template<bool HAS128>
__device__ __forceinline__ void maybe_renorm(float& A0, float& A1, float& A2,
                                             int& e, float& sch) {
    float m2 = fmaxf(A0, A1);
    if (HAS128) m2 = fmaxf(m2, A2);
    const bool out = (m2 > 16777216.0f) ||
                     ((m2 < 5.9604644775390625e-8f) && (m2 > 0.0f));  // 2^+-24
    if (__any(out)) {
        const float mm = (m2 == 0.0f) ? 1.0f : m2;
        const int eb = __float_as_int(mm) >> 23;           // biased exp
        const float s = __int_as_float((254 - eb) << 23);  // exact 2^(127-eb)
        A0 *= s; A1 *= s;
        if (HAS128) A2 *= s;
        e += eb - 127;
        const int ep = dppi(e);
        int d = ep - e;
        d = d < -125 ? -125 : d;
        d = d > 127 ? 127 : d;
        sch = __int_as_float((d + 126) << 23);             // 2^(d-1): sc*0.5
    }
}

template<bool HAS128>
__device__ __forceinline__ void step(float& A0, float& A1, float& A2,
                                     float sch, float skipf2, float ql) {
    const float P1 = dppf(A1) * sch;          // 0.5*sc*A1prev
    const float A0o = A0, A1o = A1;
    A0 = fmaf(A0o, 0.5f, P1);                 // 0.5*(A0 + sc*A1p)
    const float t = fmaf(skipf2, P1, A0o);    // A0 + sk*sc*A1p
    A1 = (A1o + t) * ql;                      // ql includes the 0.5
    if (HAS128) A2 = (A2 + A1o) * 0.5f;
}

template<bool HAS128>
__device__ __forceinline__ void consumer(const float (*qlbuf)[64 * QSTR],
        const float* extra, int lane, int label, int lab, int tend, int nmax,
        float* out, int b)
{
    const int lprev = __shfl_up(label, 1);
    const float skipf2 = (lane > 0 && label != lprev) ? 2.0f : 0.0f;

    float A0 = 0.0f, A1 = 0.0f, A2 = 0.0f, sch = 0.5f;
    int e = 0;

    for (int c = 0; c < nmax; ++c) {
        const float* qb = &qlbuf[c & 1][lane * QSTR];
        float qlv[32];
#pragma unroll
        for (int k = 0; k < 8; ++k) {
            const float4 t4 = *reinterpret_cast<const float4*>(qb + 4 * k);
            qlv[4*k+0] = t4.x; qlv[4*k+1] = t4.y;
            qlv[4*k+2] = t4.z; qlv[4*k+3] = t4.w;
        }
        asm volatile("s_waitcnt lgkmcnt(0)" ::: "memory");
        __builtin_amdgcn_s_barrier();          // release buffer to producer
        __builtin_amdgcn_sched_barrier(0);

        const int rem = tend - c * CHUNK;
        if (c == 0) {
            A0 = (lane == 0) ? extra[1] : 0.0f;   // t=0 init (raw, no decay)
            A1 = (lane == 0) ? extra[0] : 0.0f;
#pragma unroll
            for (int u = 1; u < 32; ++u) {
                step<HAS128>(A0, A1, A2, sch, skipf2, qlv[u]);
                if ((u & 3) == 3) maybe_renorm<HAS128>(A0, A1, A2, e, sch);
            }
        } else if (rem >= CHUNK) {
#pragma unroll
            for (int u = 0; u < 32; ++u) {
                step<HAS128>(A0, A1, A2, sch, skipf2, qlv[u]);
                if ((u & 3) == 3) maybe_renorm<HAS128>(A0, A1, A2, e, sch);
            }
        } else {
            for (int u = 0; u < rem; ++u) {        // short tail, once
                step<HAS128>(A0, A1, A2, sch, skipf2, qlv[u]);
                if ((u & 3) == 3) maybe_renorm<HAS128>(A0, A1, A2, e, sch);
            }
        }
    }
    __builtin_amdgcn_s_barrier();              // BF: lg ready
    const float lg = extra[2];
    const float ef = (float)e + lg + (float)(tend - 1);   // decay accounting
    const float l0 = LOG2(A0) + ef;
    const float l1 = LOG2(A1) + ef;
    const float a_prev = __shfl(l1, lab - 1);             // state 2*lab-1
    float a_last;
    if (HAS128) {
        const float l2 = LOG2(A2) + ef;
        a_last = __shfl(l2, 63);                          // state 128
    } else {
        a_last = __shfl(l0, lab);                         // state 2*lab
    }
    if (lane == 0) out[b] = -LN2F * lse2_2(a_last, a_prev);
}

__global__ __launch_bounds__(128) void ctc_fwd_kernel(
    const int* __restrict__ y_true, const float* __restrict__ y_pred,
    const int* __restrict__ input_len, const int* __restrict__ label_len,
    float* __restrict__ out)
{
    __shared__ __align__(16) float raw[2][CHUNK * C_];     // 32 KB
    __shared__ __align__(16) float qlbuf[2][64 * QSTR];    // 18.4 KB
    __shared__ float extra[4];                             // A1init, A0init, lg

    const int b = blockIdx.x;
    const int tid = threadIdx.x;
    const int lane = tid & 63;
    const float* __restrict__ Pg = y_pred + (size_t)b * T_ * C_;
    const int label = y_true[b * L_ + lane];
    const int in_len = input_len[b];
    const int tend = in_len < T_ ? in_len : T_;            // >= 256
    const int nmax = (tend + CHUNK - 1) / CHUNK;           // 8..16

    if (tid >= 64) {
        // ------------------------- producer (wave 1) -------------------------
        float llg = 0.0f;
        stage_chunk(Pg, &raw[0][0], lane);
        stage_chunk(Pg + CHUNK * C_, &raw[1][0], lane);
        asm volatile("s_waitcnt vmcnt(16)" ::: "memory");  // chunk0 raw ready
        produce_chunk(&raw[0][0], &qlbuf[0][0], lane, label, 0, tend, llg);
        if (lane == 0) {
            extra[0] = raw[0][label] + EPSF;               // A1 init (s=1)
            extra[1] = raw[0][BLANK_] + EPSF;              // A0 init (s=0)
        }
        asm volatile("s_waitcnt lgkmcnt(0)" ::: "memory");
        __builtin_amdgcn_s_barrier();                      // B0
        for (int c = 0; c < nmax; ++c) {
            if (c + 2 < nmax)
                stage_chunk(Pg + (size_t)(c + 2) * CHUNK * C_, &raw[c & 1][0], lane);
            if (c + 1 < nmax) {
                if (c + 2 < nmax) asm volatile("s_waitcnt vmcnt(16)" ::: "memory");
                else              asm volatile("s_waitcnt vmcnt(0)" ::: "memory");
                produce_chunk(&raw[(c + 1) & 1][0], &qlbuf[(c + 1) & 1][0],
                              lane, label, (c + 1) * CHUNK, tend, llg);
            }
            asm volatile("s_waitcnt lgkmcnt(0)" ::: "memory");
            __builtin_amdgcn_s_barrier();                  // per-chunk
        }
#pragma unroll
        for (int off = 16; off >= 1; off >>= 1) llg += __shfl_xor(llg, off);
        if (lane == 0) extra[2] = llg;                     // lg
        asm volatile("s_waitcnt lgkmcnt(0)" ::: "memory");
        __builtin_amdgcn_s_barrier();                      // BF
    } else {
        // ------------------------- consumer (wave 0) -------------------------
        const int lab = label_len[b];
        __builtin_amdgcn_s_barrier();                      // B0
        if (lab == L_) consumer<true >(qlbuf, extra, lane, label, lab, tend, nmax, out, b);
        else           consumer<false>(qlbuf, extra, lane, label, lab, tend, nmax, out, b);
    }
}

extern "C" void kernel_launch(void* const* d_in, const int* in_sizes, int n_in,
                              void* d_out, int out_size, void* d_ws, size_t ws_size,
                              hipStream_t stream) {
    const int*   y_true    = (const int*)d_in[0];
    const float* y_pred    = (const float*)d_in[1];
    const int*   input_len = (const int*)d_in[2];
    const int*   label_len = (const int*)d_in[3];
    float* out = (float*)d_out;

    ctc_fwd_kernel<<<B_, 128, 0, stream>>>(y_true, y_pred, input_len, label_len, out);
}